// Round 1
// baseline (669.541 us; speedup 1.0000x reference)
//
#include <hip/hip_runtime.h>
#include <hip/hip_bf16.h>

#define N_NODES 50000
#define N_EDGES 500000
#define D 128          // NODE_DIM == EDGE_DIM
#define OUTD 256       // 2*EDGE_DIM

typedef float f32x4 __attribute__((ext_vector_type(4)));
typedef unsigned int u32x4 __attribute__((ext_vector_type(4)));
typedef __bf16 bf16x8 __attribute__((ext_vector_type(8)));

__device__ __forceinline__ unsigned short f2bf(float x) {
    unsigned u = __float_as_uint(x);
    unsigned r = (u + 0x7fffu + ((u >> 16) & 1u)) >> 16;
    return (unsigned short)r;
}

// ---------------- kernel 0: per-node LayerNorm, f32 -> bf16 ----------------
__global__ __launch_bounds__(256) void node_ln(
    const float* __restrict__ x, const float* __restrict__ gamma,
    const float* __restrict__ beta, unsigned short* __restrict__ xn)
{
    int w = threadIdx.x >> 6, lane = threadIdx.x & 63;
    int row = blockIdx.x * 4 + w;                       // 12500*4 == 50000 exact
    const float2 v = *(const float2*)(x + (size_t)row * D + lane * 2);
    float s = v.x + v.y;
    float q = v.x * v.x + v.y * v.y;
#pragma unroll
    for (int m = 1; m < 64; m <<= 1) {
        s += __shfl_xor(s, m, 64);
        q += __shfl_xor(q, m, 64);
    }
    float mean = s * (1.f / 128.f);
    float var = q * (1.f / 128.f) - mean * mean;
    float rs = rsqrtf(var + 1e-5f);
    float2 gg = *(const float2*)(gamma + lane * 2);
    float2 bb = *(const float2*)(beta + lane * 2);
    float y0 = (v.x - mean) * rs * gg.x + bb.x;
    float y1 = (v.y - mean) * rs * gg.y + bb.y;
    unsigned int pack = (unsigned)f2bf(y0) | ((unsigned)f2bf(y1) << 16);
    *(unsigned int*)(xn + (size_t)row * D + lane * 2) = pack;
}

// ------------- kernel 1: repack W f32[384][256] -> bf16 fragment order -----
// Wp layout: [k>>3][col][k&7]  (per 128-k chunk of 32768 ushorts)
__global__ __launch_bounds__(256) void repack_w(
    const float* __restrict__ W, unsigned short* __restrict__ Wp)
{
    int tid = blockIdx.x * 256 + threadIdx.x;           // 98304 total
    int k = tid >> 8;
    int col = tid & 255;
    float v = W[tid];
    int dst = (k >> 3) * 2048 + col * 8 + (k & 7);
    Wp[dst] = f2bf(v);
}

// ---------------- kernel 2: fused edge update ------------------------------
__global__ __launch_bounds__(512) void edge_kernel(
    const unsigned short* __restrict__ xn, const unsigned short* __restrict__ Wp,
    const int* __restrict__ eidx, const float* __restrict__ ea,
    const float* __restrict__ bias, const float* __restrict__ egamma,
    const float* __restrict__ ebeta, float* __restrict__ out)
{
    __shared__ unsigned short A_lds[128 * 128];   // 32 KB, XOR-swizzled rows
    __shared__ unsigned short B_lds[32768];       // 64 KB, packed fragment order
    __shared__ float red_s[128 * 4];
    __shared__ float red_q[128 * 4];

    const int t = threadIdx.x;
    const int lane = t & 63;
    const int w = t >> 6;
    const int wm = w >> 2, wn = w & 3;            // 2 x 4 wave grid
    const int lhi = lane >> 4, llo = lane & 15;
    const int e0 = blockIdx.x * 128;

    f32x4 acc[4][4];
#pragma unroll
    for (int a = 0; a < 4; ++a)
#pragma unroll
        for (int b2 = 0; b2 < 4; ++b2)
            acc[a][b2] = f32x4{0.f, 0.f, 0.f, 0.f};

    const int srow = t >> 2;                      // staging: 4 threads per row
    const int sq4 = t & 3;
    const int se = (e0 + srow < N_EDGES) ? (e0 + srow) : (N_EDGES - 1);

    for (int chunk = 0; chunk < 3; ++chunk) {
        // ---- stage A: 128 rows x 128 k (bf16), swizzled ----
        if (chunk < 2) {
            const int node = eidx[chunk * N_EDGES + se];
            const u32x4* src = (const u32x4*)(xn + (size_t)node * D);
#pragma unroll
            for (int c = 0; c < 4; ++c) {
                int q16 = sq4 * 4 + c;
                u32x4 v = src[q16];
                *(u32x4*)((char*)A_lds + srow * 256 + ((q16 ^ (srow & 7)) << 4)) = v;
            }
        } else {
            const float* src = ea + (size_t)se * D;
#pragma unroll
            for (int c = 0; c < 4; ++c) {
                int q16 = sq4 * 4 + c;
                f32x4 v0 = *(const f32x4*)(src + q16 * 8);
                f32x4 v1 = *(const f32x4*)(src + q16 * 8 + 4);
                u32x4 p;
                p.x = (unsigned)f2bf(v0.x) | ((unsigned)f2bf(v0.y) << 16);
                p.y = (unsigned)f2bf(v0.z) | ((unsigned)f2bf(v0.w) << 16);
                p.z = (unsigned)f2bf(v1.x) | ((unsigned)f2bf(v1.y) << 16);
                p.w = (unsigned)f2bf(v1.z) | ((unsigned)f2bf(v1.w) << 16);
                *(u32x4*)((char*)A_lds + srow * 256 + ((q16 ^ (srow & 7)) << 4)) = p;
            }
        }
        // ---- stage B: 64 KB linear copy of packed W chunk ----
        {
            const u32x4* wp = (const u32x4*)(Wp + chunk * 32768);
#pragma unroll
            for (int i = 0; i < 8; ++i) {
                int idx = i * 512 + t;
                *(u32x4*)((char*)B_lds + idx * 16) = wp[idx];
            }
        }
        __syncthreads();
        // ---- MFMA: 4 k-steps of 32, 4x4 tiles of 16x16 per wave ----
#pragma unroll
        for (int kq = 0; kq < 4; ++kq) {
            bf16x8 af[4], bfr[4];
#pragma unroll
            for (int mt = 0; mt < 4; ++mt) {
                int row = wm * 64 + mt * 16 + llo;
                int slot = (kq * 4 + lhi) ^ (row & 7);
                af[mt] = *(const bf16x8*)((char*)A_lds + row * 256 + (slot << 4));
            }
#pragma unroll
            for (int nt = 0; nt < 4; ++nt) {
                int colb = (nt < 2) ? (wn * 32 + nt * 16)
                                    : (128 + wn * 32 + (nt - 2) * 16);
                int col = colb + llo;
                bfr[nt] = *(const bf16x8*)((char*)B_lds + ((kq * 4 + lhi) * 256 + col) * 16);
            }
#pragma unroll
            for (int mt = 0; mt < 4; ++mt)
#pragma unroll
                for (int nt = 0; nt < 4; ++nt)
                    acc[mt][nt] = __builtin_amdgcn_mfma_f32_16x16x32_bf16(
                        af[mt], bfr[nt], acc[mt][nt], 0, 0, 0);
        }
        __syncthreads();
    }

    // ---- epilogue: bias+relu, register-local gating, cross-wave LN ----
    const int c0 = wn * 32 + llo;       // delta col (gate col = c0+128, same lane)
    const int c1 = c0 + 16;
    const float b_d0 = bias[c0], b_d1 = bias[c1];
    const float b_g0 = bias[128 + c0], b_g1 = bias[128 + c1];
    const float g0 = egamma[c0], g1 = egamma[c1];
    const float be0 = ebeta[c0], be1 = ebeta[c1];

    float o0[4][4], o1[4][4];
#pragma unroll
    for (int mt = 0; mt < 4; ++mt) {
#pragma unroll
        for (int i = 0; i < 4; ++i) {
            int rl = wm * 64 + mt * 16 + lhi * 4 + i;
            int e = e0 + rl;
            int ecl = (e < N_EDGES) ? e : (N_EDGES - 1);
            float rd0 = fmaxf(acc[mt][0][i] + b_d0, 0.f);
            float rd1 = fmaxf(acc[mt][1][i] + b_d1, 0.f);
            float rg0 = fmaxf(acc[mt][2][i] + b_g0, 0.f);
            float rg1 = fmaxf(acc[mt][3][i] + b_g1, 0.f);
            float ea0 = ea[(size_t)ecl * D + c0];
            float ea1 = ea[(size_t)ecl * D + c1];
            float v0 = ea0 + rd0 / (1.f + __expf(-rg0));
            float v1 = ea1 + rd1 / (1.f + __expf(-rg1));
            o0[mt][i] = v0;
            o1[mt][i] = v1;
            float s = v0 + v1, q = v0 * v0 + v1 * v1;
#pragma unroll
            for (int m = 1; m < 16; m <<= 1) {
                s += __shfl_xor(s, m, 64);
                q += __shfl_xor(q, m, 64);
            }
            if (llo == 0) {
                red_s[rl * 4 + wn] = s;
                red_q[rl * 4 + wn] = q;
            }
        }
    }
    __syncthreads();
#pragma unroll
    for (int mt = 0; mt < 4; ++mt) {
#pragma unroll
        for (int i = 0; i < 4; ++i) {
            int rl = wm * 64 + mt * 16 + lhi * 4 + i;
            int e = e0 + rl;
            float s = red_s[rl * 4 + 0] + red_s[rl * 4 + 1] +
                      red_s[rl * 4 + 2] + red_s[rl * 4 + 3];
            float q = red_q[rl * 4 + 0] + red_q[rl * 4 + 1] +
                      red_q[rl * 4 + 2] + red_q[rl * 4 + 3];
            float mean = s * (1.f / 128.f);
            float var = q * (1.f / 128.f) - mean * mean;
            float rs = rsqrtf(var + 1e-5f);
            float y0 = (o0[mt][i] - mean) * rs * g0 + be0;
            float y1 = (o1[mt][i] - mean) * rs * g1 + be1;
            if (e < N_EDGES) {
                out[(size_t)e * D + c0] = y0;
                out[(size_t)e * D + c1] = y1;
            }
        }
    }
}

extern "C" void kernel_launch(void* const* d_in, const int* in_sizes, int n_in,
                              void* d_out, int out_size, void* d_ws, size_t ws_size,
                              hipStream_t stream)
{
    const float* x = (const float*)d_in[0];
    const int* eidx = (const int*)d_in[1];
    const float* ea = (const float*)d_in[2];
    const float* W = (const float*)d_in[3];
    const float* b = (const float*)d_in[4];
    const float* ngamma = (const float*)d_in[5];
    const float* nbeta = (const float*)d_in[6];
    const float* egamma = (const float*)d_in[7];
    const float* ebeta = (const float*)d_in[8];
    float* out = (float*)d_out;

    unsigned short* xn = (unsigned short*)d_ws;          // 50000*128 bf16 = 12.8 MB
    unsigned short* Wp = xn + (size_t)N_NODES * D;       // 98304 bf16 = 192 KB

    node_ln<<<N_NODES / 4, 256, 0, stream>>>(x, ngamma, nbeta, xn);
    repack_w<<<384, 256, 0, stream>>>(W, Wp);
    edge_kernel<<<(N_EDGES + 127) / 128, 512, 0, stream>>>(
        xn, Wp, eidx, ea, b, egamma, ebeta, out);
}

// Round 3
// 596.106 us; speedup vs baseline: 1.1232x; 1.1232x over previous
//
#include <hip/hip_runtime.h>
#include <hip/hip_bf16.h>

#define N_NODES 50000
#define N_EDGES 500000
#define D 128          // NODE_DIM == EDGE_DIM
#define OUTD 256       // 2*EDGE_DIM

typedef float f32x4 __attribute__((ext_vector_type(4)));
typedef unsigned int u32x4 __attribute__((ext_vector_type(4)));
typedef __bf16 bf16x8 __attribute__((ext_vector_type(8)));

__device__ __forceinline__ unsigned short f2bf(float x) {
    unsigned u = __float_as_uint(x);
    unsigned r = (u + 0x7fffu + ((u >> 16) & 1u)) >> 16;
    return (unsigned short)r;
}

__device__ __forceinline__ void gload_lds16(const void* g, void* l) {
    __builtin_amdgcn_global_load_lds(
        (const __attribute__((address_space(1))) unsigned int*)g,
        (__attribute__((address_space(3))) unsigned int*)l,
        16, 0, 0);
}

// ---------------- kernel 0: per-node LayerNorm, f32 -> bf16 ----------------
__global__ __launch_bounds__(256) void node_ln(
    const float* __restrict__ x, const float* __restrict__ gamma,
    const float* __restrict__ beta, unsigned short* __restrict__ xn)
{
    int w = threadIdx.x >> 6, lane = threadIdx.x & 63;
    int row = blockIdx.x * 4 + w;                       // 12500*4 == 50000 exact
    const float2 v = *(const float2*)(x + (size_t)row * D + lane * 2);
    float s = v.x + v.y;
    float q = v.x * v.x + v.y * v.y;
#pragma unroll
    for (int m = 1; m < 64; m <<= 1) {
        s += __shfl_xor(s, m, 64);
        q += __shfl_xor(q, m, 64);
    }
    float mean = s * (1.f / 128.f);
    float var = q * (1.f / 128.f) - mean * mean;
    float rs = rsqrtf(var + 1e-5f);
    float2 gg = *(const float2*)(gamma + lane * 2);
    float2 bb = *(const float2*)(beta + lane * 2);
    float y0 = (v.x - mean) * rs * gg.x + bb.x;
    float y1 = (v.y - mean) * rs * gg.y + bb.y;
    unsigned int pack = (unsigned)f2bf(y0) | ((unsigned)f2bf(y1) << 16);
    *(unsigned int*)(xn + (size_t)row * D + lane * 2) = pack;
}

// ------------- kernel 1: repack W f32[384][256] -> bf16 fragment order -----
// Wp layout: [k>>3][col][k&7]  (per 128-k chunk of 32768 ushorts)
__global__ __launch_bounds__(256) void repack_w(
    const float* __restrict__ W, unsigned short* __restrict__ Wp)
{
    int tid = blockIdx.x * 256 + threadIdx.x;           // 98304 total
    int k = tid >> 8;
    int col = tid & 255;
    float v = W[tid];
    int dst = (k >> 3) * 2048 + col * 8 + (k & 7);
    Wp[dst] = f2bf(v);
}

// ---------------- kernel 2: fused edge update ------------------------------
__global__ __launch_bounds__(512, 4) void edge_kernel(
    const unsigned short* __restrict__ xn, const unsigned short* __restrict__ Wp,
    const int* __restrict__ eidx, const float* __restrict__ ea,
    const float* __restrict__ bias, const float* __restrict__ egamma,
    const float* __restrict__ ebeta, float* __restrict__ out)
{
    __shared__ __align__(16) unsigned short A_lds[128 * 128];  // 32 KB swizzled
    __shared__ float red_s[128 * 4];
    __shared__ float red_q[128 * 4];

    const int t = threadIdx.x;
    const int lane = t & 63;
    const int w = t >> 6;
    const int wm = w >> 2, wn = w & 3;            // 2 x 4 wave grid
    const int lhi = lane >> 4, llo = lane & 15;
    const int e0 = blockIdx.x * 128;

    f32x4 acc[4][4];
#pragma unroll
    for (int a = 0; a < 4; ++a)
#pragma unroll
        for (int b2 = 0; b2 < 4; ++b2)
            acc[a][b2] = f32x4{0.f, 0.f, 0.f, 0.f};

    const int srow = t >> 2;                      // chunk-2 staging: 4 thr/row
    const int sq4 = t & 3;
    const int se = (e0 + srow < N_EDGES) ? (e0 + srow) : (N_EDGES - 1);

    for (int chunk = 0; chunk < 3; ++chunk) {
        if (chunk < 2) {
            // ---- A gather via global_load_lds: linear LDS dest, inverse-
            // swizzled per-lane global source (rule 21) ----
            const int rb = w * 16;                // 8 waves x 16 rows
#pragma unroll
            for (int c = 0; c < 4; ++c) {
                const int rloc = rb + c * 4 + lhi;
                const int e = e0 + rloc;
                const int ecl = (e < N_EDGES) ? e : (N_EDGES - 1);
                const int node = eidx[chunk * N_EDGES + ecl];
                const char* src = (const char*)(xn + (size_t)node * D)
                                + ((llo ^ (rloc & 7)) << 4);
                gload_lds16(src, (char*)A_lds + (rb + c * 4) * 256);
            }
        } else {
            // ---- edge_attr: f32 load + convert + swizzled ds_write ----
            const float* src = ea + (size_t)se * D;
#pragma unroll
            for (int c = 0; c < 4; ++c) {
                int q16 = sq4 * 4 + c;
                f32x4 v0 = *(const f32x4*)(src + q16 * 8);
                f32x4 v1 = *(const f32x4*)(src + q16 * 8 + 4);
                u32x4 p;
                p.x = (unsigned)f2bf(v0.x) | ((unsigned)f2bf(v0.y) << 16);
                p.y = (unsigned)f2bf(v0.z) | ((unsigned)f2bf(v0.w) << 16);
                p.z = (unsigned)f2bf(v1.x) | ((unsigned)f2bf(v1.y) << 16);
                p.w = (unsigned)f2bf(v1.z) | ((unsigned)f2bf(v1.w) << 16);
                *(u32x4*)((char*)A_lds + srow * 256 + ((q16 ^ (srow & 7)) << 4)) = p;
            }
        }
        __syncthreads();
        // ---- MFMA: B fragments straight from L2 (identical across blocks) --
        const unsigned short* wb = Wp + (size_t)chunk * 32768;
#pragma unroll
        for (int kq = 0; kq < 4; ++kq) {
            bf16x8 af[4], bfr[4];
#pragma unroll
            for (int nt = 0; nt < 4; ++nt) {
                int colb = (nt < 2) ? (wn * 32 + nt * 16)
                                    : (128 + wn * 32 + (nt - 2) * 16);
                bfr[nt] = *(const bf16x8*)(wb + (kq * 4 + lhi) * 2048
                                              + (colb + llo) * 8);
            }
#pragma unroll
            for (int mt = 0; mt < 4; ++mt) {
                int row = wm * 64 + mt * 16 + llo;
                int slot = (kq * 4 + lhi) ^ (row & 7);
                af[mt] = *(const bf16x8*)((char*)A_lds + row * 256 + (slot << 4));
            }
#pragma unroll
            for (int mt = 0; mt < 4; ++mt)
#pragma unroll
                for (int nt = 0; nt < 4; ++nt)
                    acc[mt][nt] = __builtin_amdgcn_mfma_f32_16x16x32_bf16(
                        af[mt], bfr[nt], acc[mt][nt], 0, 0, 0);
        }
        __syncthreads();
    }

    // ---- epilogue: bias+relu, register-local gating, cross-wave LN ----
    const int c0 = wn * 32 + llo;       // delta col (gate col = c0+128, same lane)
    const int c1 = c0 + 16;
    const float b_d0 = bias[c0], b_d1 = bias[c1];
    const float b_g0 = bias[128 + c0], b_g1 = bias[128 + c1];
    const float g0 = egamma[c0], g1 = egamma[c1];
    const float be0 = ebeta[c0], be1 = ebeta[c1];
    const int q0 = c0 >> 3, q1 = c1 >> 3;   // 16B slot of residual cols
    const int o0b = (c0 & 7) * 2, o1b = (c1 & 7) * 2;

    float o0[4][4], o1[4][4];
#pragma unroll
    for (int mt = 0; mt < 4; ++mt) {
#pragma unroll
        for (int i = 0; i < 4; ++i) {
            int rl = wm * 64 + mt * 16 + lhi * 4 + i;
            float rd0 = fmaxf(acc[mt][0][i] + b_d0, 0.f);
            float rd1 = fmaxf(acc[mt][1][i] + b_d1, 0.f);
            float rg0 = fmaxf(acc[mt][2][i] + b_g0, 0.f);
            float rg1 = fmaxf(acc[mt][3][i] + b_g1, 0.f);
            // residual from chunk-2 A_lds (bf16 edge_attr, still resident)
            unsigned short u0 = *(const unsigned short*)((const char*)A_lds
                + rl * 256 + ((q0 ^ (rl & 7)) << 4) + o0b);
            unsigned short u1 = *(const unsigned short*)((const char*)A_lds
                + rl * 256 + ((q1 ^ (rl & 7)) << 4) + o1b);
            float ea0 = __uint_as_float((unsigned)u0 << 16);
            float ea1 = __uint_as_float((unsigned)u1 << 16);
            float v0 = ea0 + rd0 / (1.f + __expf(-rg0));
            float v1 = ea1 + rd1 / (1.f + __expf(-rg1));
            o0[mt][i] = v0;
            o1[mt][i] = v1;
            float s = v0 + v1, q = v0 * v0 + v1 * v1;
#pragma unroll
            for (int m = 1; m < 16; m <<= 1) {
                s += __shfl_xor(s, m, 64);
                q += __shfl_xor(q, m, 64);
            }
            if (llo == 0) {
                red_s[rl * 4 + wn] = s;
                red_q[rl * 4 + wn] = q;
            }
        }
    }
    __syncthreads();
#pragma unroll
    for (int mt = 0; mt < 4; ++mt) {
#pragma unroll
        for (int i = 0; i < 4; ++i) {
            int rl = wm * 64 + mt * 16 + lhi * 4 + i;
            int e = e0 + rl;
            float s = red_s[rl * 4 + 0] + red_s[rl * 4 + 1] +
                      red_s[rl * 4 + 2] + red_s[rl * 4 + 3];
            float q = red_q[rl * 4 + 0] + red_q[rl * 4 + 1] +
                      red_q[rl * 4 + 2] + red_q[rl * 4 + 3];
            float mean = s * (1.f / 128.f);
            float var = q * (1.f / 128.f) - mean * mean;
            float rs = rsqrtf(var + 1e-5f);
            float y0 = (o0[mt][i] - mean) * rs * g0 + be0;
            float y1 = (o1[mt][i] - mean) * rs * g1 + be1;
            if (e < N_EDGES) {
                out[(size_t)e * D + c0] = y0;
                out[(size_t)e * D + c1] = y1;
            }
        }
    }
}

extern "C" void kernel_launch(void* const* d_in, const int* in_sizes, int n_in,
                              void* d_out, int out_size, void* d_ws, size_t ws_size,
                              hipStream_t stream)
{
    const float* x = (const float*)d_in[0];
    const int* eidx = (const int*)d_in[1];
    const float* ea = (const float*)d_in[2];
    const float* W = (const float*)d_in[3];
    const float* b = (const float*)d_in[4];
    const float* ngamma = (const float*)d_in[5];
    const float* nbeta = (const float*)d_in[6];
    const float* egamma = (const float*)d_in[7];
    const float* ebeta = (const float*)d_in[8];
    float* out = (float*)d_out;

    unsigned short* xn = (unsigned short*)d_ws;          // 50000*128 bf16 = 12.8 MB
    unsigned short* Wp = xn + (size_t)N_NODES * D;       // 98304 bf16 = 192 KB

    node_ln<<<N_NODES / 4, 256, 0, stream>>>(x, ngamma, nbeta, xn);
    repack_w<<<384, 256, 0, stream>>>(W, Wp);
    edge_kernel<<<(N_EDGES + 127) / 128, 512, 0, stream>>>(
        xn, Wp, eidx, ea, b, egamma, ebeta, out);
}